// Round 6
// baseline (495.386 us; speedup 1.0000x reference)
//
#include <hip/hip_runtime.h>

typedef unsigned short u16;
typedef unsigned int u32;
typedef unsigned long long u64;
typedef __attribute__((ext_vector_type(8))) short short8;
typedef __attribute__((ext_vector_type(4))) float floatx4;

// ---- bf16 <-> f32 helpers (raw bits, RNE) ----
__device__ __forceinline__ float bf2f(u16 u) {
    u32 x = ((u32)u) << 16;
    float f;
    __builtin_memcpy(&f, &x, 4);
    return f;
}
__device__ __forceinline__ u16 f2bf(float f) {
    u32 x;
    __builtin_memcpy(&x, &f, 4);
    u32 r = (x + 0x7fffu + ((x >> 16) & 1u)) >> 16;
    return (u16)r;
}

// ==========================================================================
// Convert f32 -> bf16, 4 elems/thread
// ==========================================================================
__global__ __launch_bounds__(256) void convert_x(const float* __restrict__ in,
                                                 u16* __restrict__ out) {
    int i = blockIdx.x * 256 + threadIdx.x;
    float4 v = *(const float4*)(in + (size_t)i * 4);
    u16 o[4] = {f2bf(v.x), f2bf(v.y), f2bf(v.z), f2bf(v.w)};
    *(u64*)(out + (size_t)i * 4) = *(u64*)o;
}

// ==========================================================================
// All four weight transposes in one launch (z selects matrix).
// in f32 (R x C) -> out bf16 (C x R); R=2048 for all.
// ==========================================================================
__global__ __launch_bounds__(1024) void transpose_wall(const float* __restrict__ Wq,
                                                       const float* __restrict__ Wk,
                                                       const float* __restrict__ Wv,
                                                       const float* __restrict__ Wo,
                                                       u16* __restrict__ WqkvT,
                                                       u16* __restrict__ WoT) {
    const int z = blockIdx.z;
    const float* in;
    u16* out;
    int C;
    if (z == 0) { in = Wq; out = WqkvT; C = 2048; }
    else if (z == 1) { in = Wk; out = WqkvT + 2048 * 2048; C = 1024; }
    else if (z == 2) { in = Wv; out = WqkvT + 3072 * 2048; C = 1024; }
    else { in = Wo; out = WoT; C = 2048; }
    const int c0 = blockIdx.x * 32, r0 = blockIdx.y * 32;
    if (c0 >= C) return;
    __shared__ u16 t[32][33];
    const int tx = threadIdx.x, ty = threadIdx.y;
    t[ty][tx] = f2bf(in[(size_t)(r0 + ty) * C + c0 + tx]);
    __syncthreads();
    out[(size_t)(c0 + ty) * 2048 + r0 + tx] = t[tx][ty];
}

// V inside QKV (b,s,4096 row: [Q2048|K1024|V1024]) -> Vt (b,kv,d,s)
__global__ __launch_bounds__(1024) void transpose_v(const u16* __restrict__ QKV,
                                                    u16* __restrict__ Vt) {
    __shared__ u16 t[32][33];
    const int tx = threadIdx.x, ty = threadIdx.y;
    const int b = blockIdx.z >> 3, kv = blockIdx.z & 7;
    const int s0 = blockIdx.x * 32, d0 = blockIdx.y * 32;
    t[ty][tx] = QKV[(size_t)(b * 2048 + s0 + ty) * 4096 + 3072 + kv * 128 + d0 + tx];
    __syncthreads();
    Vt[(size_t)((b * 8 + kv) * 128 + d0 + ty) * 2048 + s0 + tx] = t[tx][ty];
}

// ==========================================================================
// GEMM: C[M,N] = A[M,K] @ Bt[N,K]^T (bf16 in, fp32 acc, OUT_T out)
// tile 128x128, BK=64, 256 threads; global_load_lds width-16 staging (m97)
// ==========================================================================
template <typename OUT_T>
__global__ __launch_bounds__(256) void gemm_bt(const u16* __restrict__ A,
                                               const u16* __restrict__ Bt,
                                               OUT_T* __restrict__ C,
                                               int M, int N, int K) {
    __shared__ __align__(16) u16 As[128 * 64];
    __shared__ __align__(16) u16 Bs[128 * 64];
    const int tid = threadIdx.x;
    const int wave = tid >> 6, lane = tid & 63;
    const int lr = lane & 15, lq = lane >> 4;
    const int m0 = blockIdx.y * 128, n0 = blockIdx.x * 128;
    const int wr = (wave >> 1) * 64, wc = (wave & 1) * 64;

    floatx4 zf = {0.f, 0.f, 0.f, 0.f};
    floatx4 acc[4][4];
#pragma unroll
    for (int i = 0; i < 4; i++)
#pragma unroll
        for (int j = 0; j < 4; j++) acc[i][j] = zf;

    const int lrow = lane >> 3;          // 0..7 within chunk
    const int lcol = (lane & 7) << 3;    // 0..56

    for (int k0 = 0; k0 < K; k0 += 64) {
        __syncthreads();  // protect As/Bs from overwrite while previous iter reads
#pragma unroll
        for (int c = 0; c < 4; c++) {
            int chunk = (wave << 2) + c;          // 0..15
            int row = (chunk << 3) + lrow;        // 0..127
            __builtin_amdgcn_global_load_lds(
                (const __attribute__((address_space(1))) void*)(A + (size_t)(m0 + row) * K + k0 + lcol),
                (__attribute__((address_space(3))) void*)(As + (chunk << 9)), 16, 0, 0);
            __builtin_amdgcn_global_load_lds(
                (const __attribute__((address_space(1))) void*)(Bt + (size_t)(n0 + row) * K + k0 + lcol),
                (__attribute__((address_space(3))) void*)(Bs + (chunk << 9)), 16, 0, 0);
        }
        __syncthreads();  // vmcnt(0) drain makes staged data visible
#pragma unroll
        for (int kk = 0; kk < 64; kk += 32) {
            short8 af[4], bfr[4];
#pragma unroll
            for (int i = 0; i < 4; i++)
                af[i] = *(const short8*)(As + (wr + i * 16 + lr) * 64 + kk + lq * 8);
#pragma unroll
            for (int j = 0; j < 4; j++)
                bfr[j] = *(const short8*)(Bs + (wc + j * 16 + lr) * 64 + kk + lq * 8);
#pragma unroll
            for (int i = 0; i < 4; i++)
#pragma unroll
                for (int j = 0; j < 4; j++)
                    acc[i][j] = __builtin_amdgcn_mfma_f32_16x16x32_bf16(af[i], bfr[j], acc[i][j], 0, 0, 0);
        }
    }
#pragma unroll
    for (int i = 0; i < 4; i++)
#pragma unroll
        for (int j = 0; j < 4; j++)
#pragma unroll
            for (int r = 0; r < 4; r++) {
                int row = m0 + wr + i * 16 + lq * 4 + r;
                int col = n0 + wc + j * 16 + lr;
                if constexpr (sizeof(OUT_T) == 2)
                    C[(size_t)row * N + col] = f2bf(acc[i][j][r]);
                else
                    C[(size_t)row * N + col] = acc[i][j][r];
            }
}

// ==========================================================================
// RMS-norm + RoPE on Q/K inside QKV (row stride 4096), in place (bf16).
// One wave per 128-elem head row. Q also scaled by D^-0.5 * log2(e).
// ==========================================================================
__global__ __launch_bounds__(256) void norm_rope(u16* __restrict__ QKV,
                                                 const float* __restrict__ cosb,
                                                 const float* __restrict__ sinb,
                                                 const float* __restrict__ qw,
                                                 const float* __restrict__ kw) {
    const int tid = threadIdx.x;
    const int wave = tid >> 6, lane = tid & 63;
    const int t = blockIdx.x * 4 + wave;  // 0..98303
    u16* ptr;
    const float* w;
    float scale;
    int bs;
    if (t < 65536) {
        bs = t >> 4;
        ptr = QKV + (size_t)bs * 4096 + (t & 15) * 128;
        w = qw;
        scale = 0.08838834764831845f * 1.4426950408889634f;  // D^-0.5 * log2(e)
    } else {
        int t2 = t - 65536;
        bs = t2 >> 3;
        ptr = QKV + (size_t)bs * 4096 + 2048 + (t2 & 7) * 128;
        w = kw;
        scale = 1.0f;
    }
    const int d = lane * 2;
    u32 xv = *(const u32*)(ptr + d);
    float x0 = bf2f((u16)(xv & 0xffff)), x1 = bf2f((u16)(xv >> 16));
    float ss = x0 * x0 + x1 * x1;
#pragma unroll
    for (int off = 1; off < 64; off <<= 1) ss += __shfl_xor(ss, off);
    float rn = rsqrtf(ss * (1.0f / 128.0f) + 1e-6f);
    float2 wv = *(const float2*)(w + d);
    float y0 = x0 * rn * wv.x;
    float y1 = x1 * rn * wv.y;
    float p0 = __shfl_xor(y0, 32);
    float p1 = __shfl_xor(y1, 32);
    float sgn = (lane < 32) ? -1.0f : 1.0f;
    float2 cv = *(const float2*)(cosb + (size_t)bs * 128 + d);
    float2 sv = *(const float2*)(sinb + (size_t)bs * 128 + d);
    float o0 = (y0 * cv.x + sgn * p0 * sv.x) * scale;
    float o1 = (y1 * cv.y + sgn * p1 * sv.y) * scale;
    *(u32*)(ptr + d) = (u32)f2bf(o0) | ((u32)f2bf(o1) << 16);
}

// ==========================================================================
// Causal GQA flash attention, transposed-score formulation, SW-pipelined:
// K/V tile kt+1 is prefetched into registers while tile kt computes, so
// global latency overlaps MFMA instead of sitting between the barriers.
// grid (S/128, NH, B), 512 thr = 8 waves x 16 q-rows; key tile 64.
// ==========================================================================
__global__ __launch_bounds__(512, 2) void attn_kernel(const u16* __restrict__ QKV,
                                                      const u16* __restrict__ Vt,
                                                      u16* __restrict__ O) {
    __shared__ __align__(16) u16 Ks[64 * 136];   // [key][d]  pad 136
    __shared__ __align__(16) u16 Vs[128 * 72];   // [d][key]  pad 72
    __shared__ __align__(16) u16 Ps[128 * 72];   // [qrow][key] pad 72
    const int tid = threadIdx.x;
    const int wave = tid >> 6, lane = tid & 63;
    const int lr = lane & 15, lq = lane >> 4;
    const int qt = 15 - blockIdx.x;  // heavy tiles dispatch first
    const int h = blockIdx.y, b = blockIdx.z;
    const int kv = h >> 1;
    const int q0 = qt * 128;
    const int wq = wave * 16;

    // Q fragments in registers (B-operand: n=qrow on lr, k=d on lq*8+j)
    short8 qf[4];
#pragma unroll
    for (int t = 0; t < 4; t++)
        qf[t] = *(const short8*)(QKV + (size_t)(b * 2048 + q0 + wq + lr) * 4096 + h * 128 + t * 32 + lq * 8);

    floatx4 zf = {0.f, 0.f, 0.f, 0.f};
    floatx4 oacc[8];
#pragma unroll
    for (int jn = 0; jn < 8; jn++) oacc[jn] = zf;
    float mstate = -1e30f;
    float lstate = 0.f;

    const int nIter = (qt + 1) * 2;

    // prefetch tile 0 into registers
    int4 rk[2], rv[2];
#pragma unroll
    for (int r = 0; r < 2; r++) {
        int idx = r * 512 + tid;  // 0..1023
        rk[r] = *(const int4*)(QKV + (size_t)(b * 2048 + (idx >> 4)) * 4096 + 2048 + kv * 128 + ((idx & 15) << 3));
        rv[r] = *(const int4*)(Vt + (size_t)((b * 8 + kv) * 128 + (idx >> 3)) * 2048 + ((idx & 7) << 3));
    }

    for (int kt = 0; kt < nIter; kt++) {
        const int k0 = kt * 64;
        // commit staged tile to LDS (waits vmcnt for rk/rv automatically)
#pragma unroll
        for (int r = 0; r < 2; r++) {
            int idx = r * 512 + tid;
            *(int4*)(Ks + (idx >> 4) * 136 + ((idx & 15) << 3)) = rk[r];
            *(int4*)(Vs + (idx >> 3) * 72 + ((idx & 7) << 3)) = rv[r];
        }
        __syncthreads();

        // issue next tile's global loads now; they complete during compute
        if (kt + 1 < nIter) {
            const int k0n = k0 + 64;
#pragma unroll
            for (int r = 0; r < 2; r++) {
                int idx = r * 512 + tid;
                rk[r] = *(const int4*)(QKV + (size_t)(b * 2048 + k0n + (idx >> 4)) * 4096 + 2048 + kv * 128 + ((idx & 15) << 3));
                rv[r] = *(const int4*)(Vt + (size_t)((b * 8 + kv) * 128 + (idx >> 3)) * 2048 + k0n + ((idx & 7) << 3));
            }
        }

        // wave-level causal skip: this wave's 16 q-rows all < k0 -> zero tile
        if (k0 <= q0 + wq + 15) {
            // S^T = K @ Q^T : sacc[jm]; key = jm*16+lq*4+r, qrow = lr
            floatx4 sacc[4];
#pragma unroll
            for (int jm = 0; jm < 4; jm++) sacc[jm] = zf;
#pragma unroll
            for (int t = 0; t < 4; t++) {
                short8 a[4];
#pragma unroll
                for (int jm = 0; jm < 4; jm++)
                    a[jm] = *(const short8*)(Ks + (jm * 16 + lr) * 136 + t * 32 + lq * 8);
#pragma unroll
                for (int jm = 0; jm < 4; jm++)
                    sacc[jm] = __builtin_amdgcn_mfma_f32_16x16x32_bf16(a[jm], qf[t], sacc[jm], 0, 0, 0);
            }

            // causal mask (wave-uniform branch)
            if (k0 + 63 > q0 + wq) {
#pragma unroll
                for (int jm = 0; jm < 4; jm++) {
                    int diff = (q0 + wq + lr) - (k0 + jm * 16 + lq * 4);
#pragma unroll
                    for (int r = 0; r < 4; r++)
                        if (r > diff) sacc[jm][r] = -1e30f;
                }
            }

            // online softmax per qrow (qrow on lane&15; reduce across quads)
            float mx = -1e30f;
#pragma unroll
            for (int jm = 0; jm < 4; jm++)
#pragma unroll
                for (int r = 0; r < 4; r++) mx = fmaxf(mx, sacc[jm][r]);
            mx = fmaxf(mx, __shfl_xor(mx, 16));
            mx = fmaxf(mx, __shfl_xor(mx, 32));
            float mnew = fmaxf(mstate, mx);
            float alpha = exp2f(mstate - mnew);
            mstate = mnew;
            float rs = 0.f;
#pragma unroll
            for (int jm = 0; jm < 4; jm++)
#pragma unroll
                for (int r = 0; r < 4; r++) {
                    float p = exp2f(sacc[jm][r] - mnew);
                    sacc[jm][r] = p;
                    rs += p;
                }
            rs += __shfl_xor(rs, 16);
            rs += __shfl_xor(rs, 32);
            lstate = lstate * alpha + rs;

            // P^T -> Ps[qrow][key]: lane packs 4 consecutive keys = 8B write
#pragma unroll
            for (int jm = 0; jm < 4; jm++) {
                u16 o[4] = {f2bf(sacc[jm][0]), f2bf(sacc[jm][1]),
                            f2bf(sacc[jm][2]), f2bf(sacc[jm][3])};
                *(u64*)(Ps + (wq + lr) * 72 + jm * 16 + lq * 4) = *(u64*)o;
            }

            // rescale O: alpha at qrow=lr; oacc rows at qrow=lq*4+r
            float ao[4];
#pragma unroll
            for (int r = 0; r < 4; r++) ao[r] = __shfl(alpha, lq * 4 + r);
#pragma unroll
            for (int jn = 0; jn < 8; jn++)
#pragma unroll
                for (int r = 0; r < 4; r++) oacc[jn][r] *= ao[r];

            // O += P @ V (A=P rows wq.., B=V d-rows; both b128)
#pragma unroll
            for (int t = 0; t < 2; t++) {
                short8 pa, vb[8];
                pa = *(const short8*)(Ps + (wq + lr) * 72 + t * 32 + lq * 8);
#pragma unroll
                for (int jn = 0; jn < 8; jn++)
                    vb[jn] = *(const short8*)(Vs + (jn * 16 + lr) * 72 + t * 32 + lq * 8);
#pragma unroll
                for (int jn = 0; jn < 8; jn++)
                    oacc[jn] = __builtin_amdgcn_mfma_f32_16x16x32_bf16(pa, vb[jn], oacc[jn], 0, 0, 0);
            }
        }
        __syncthreads();  // all waves done reading Ks/Vs/Ps before next commit
    }

    // epilogue: O / l   (l at qrow=lr -> transpose to qrow=lq*4+r)
    float lo[4];
#pragma unroll
    for (int r = 0; r < 4; r++) lo[r] = __shfl(lstate, lq * 4 + r);
#pragma unroll
    for (int jn = 0; jn < 8; jn++)
#pragma unroll
        for (int r = 0; r < 4; r++) {
            int row = q0 + wq + lq * 4 + r;
            O[(size_t)(b * 2048 + row) * 2048 + h * 128 + jn * 16 + lr] =
                f2bf(oacc[jn][r] / lo[r]);
        }
}

// ==========================================================================
extern "C" void kernel_launch(void* const* d_in, const int* in_sizes, int n_in,
                              void* d_out, int out_size, void* d_ws, size_t ws_size,
                              hipStream_t stream) {
    const float* X = (const float*)d_in[0];
    const float* cosb = (const float*)d_in[1];
    const float* sinb = (const float*)d_in[2];
    const float* Wq = (const float*)d_in[3];
    const float* Wk = (const float*)d_in[4];
    const float* Wv = (const float*)d_in[5];
    const float* Wo = (const float*)d_in[6];
    const float* qw = (const float*)d_in[7];
    const float* kw = (const float*)d_in[8];
    float* out = (float*)d_out;
    u16* ws = (u16*)d_ws;

    u16* WqkvT = ws;                    // 4096x2048 = 8388608
    u16* WoT = WqkvT + 8388608;         // 4194304
    u16* Xb = WoT + 4194304;            // 8388608 (dead after QKV GEMM)
    u16* QKVb = Xb + 8388608;           // 4096x4096 = 16777216
    u16* Vtb = QKVb + 16777216;         // 4194304
    u16* Ob = Xb;                       // alias
    // total 41,943,040 u16 = 83.9 MB

    dim3 tb(32, 32);
    transpose_wall<<<dim3(64, 64, 4), tb, 0, stream>>>(Wq, Wk, Wv, Wo, WqkvT, WoT);
    convert_x<<<8192, 256, 0, stream>>>(X, Xb);

    gemm_bt<u16><<<dim3(32, 32), 256, 0, stream>>>(Xb, WqkvT, QKVb, 4096, 4096, 2048);

    norm_rope<<<24576, 256, 0, stream>>>(QKVb, cosb, sinb, qw, kw);
    transpose_v<<<dim3(64, 4, 16), tb, 0, stream>>>(QKVb, Vtb);

    attn_kernel<<<dim3(16, 16, 2), 512, 0, stream>>>(QKVb, Vtb, Ob);

    gemm_bt<float><<<dim3(16, 32), 256, 0, stream>>>(Ob, WoT, out, 4096, 2048, 2048);
}

// Round 7
// 456.449 us; speedup vs baseline: 1.0853x; 1.0853x over previous
//
#include <hip/hip_runtime.h>

typedef unsigned short u16;
typedef unsigned int u32;
typedef unsigned long long u64;
typedef __attribute__((ext_vector_type(8))) short short8;
typedef __attribute__((ext_vector_type(4))) float floatx4;

#define AS1 __attribute__((address_space(1)))
#define AS3 __attribute__((address_space(3)))

// ---- bf16 <-> f32 helpers (raw bits, RNE) ----
__device__ __forceinline__ float bf2f(u16 u) {
    u32 x = ((u32)u) << 16;
    float f;
    __builtin_memcpy(&f, &x, 4);
    return f;
}
__device__ __forceinline__ u16 f2bf(float f) {
    u32 x;
    __builtin_memcpy(&x, &f, 4);
    u32 r = (x + 0x7fffu + ((x >> 16) & 1u)) >> 16;
    return (u16)r;
}

// ==========================================================================
// Convert f32 -> bf16, 4 elems/thread
// ==========================================================================
__global__ __launch_bounds__(256) void convert_x(const float* __restrict__ in,
                                                 u16* __restrict__ out) {
    int i = blockIdx.x * 256 + threadIdx.x;
    float4 v = *(const float4*)(in + (size_t)i * 4);
    u16 o[4] = {f2bf(v.x), f2bf(v.y), f2bf(v.z), f2bf(v.w)};
    *(u64*)(out + (size_t)i * 4) = *(u64*)o;
}

// ==========================================================================
// All four weight transposes in one launch (z selects matrix).
// in f32 (R x C) -> out bf16 (C x R); R=2048 for all.
// ==========================================================================
__global__ __launch_bounds__(1024) void transpose_wall(const float* __restrict__ Wq,
                                                       const float* __restrict__ Wk,
                                                       const float* __restrict__ Wv,
                                                       const float* __restrict__ Wo,
                                                       u16* __restrict__ WqkvT,
                                                       u16* __restrict__ WoT) {
    const int z = blockIdx.z;
    const float* in;
    u16* out;
    int C;
    if (z == 0) { in = Wq; out = WqkvT; C = 2048; }
    else if (z == 1) { in = Wk; out = WqkvT + 2048 * 2048; C = 1024; }
    else if (z == 2) { in = Wv; out = WqkvT + 3072 * 2048; C = 1024; }
    else { in = Wo; out = WoT; C = 2048; }
    const int c0 = blockIdx.x * 32, r0 = blockIdx.y * 32;
    if (c0 >= C) return;
    __shared__ u16 t[32][33];
    const int tx = threadIdx.x, ty = threadIdx.y;
    t[ty][tx] = f2bf(in[(size_t)(r0 + ty) * C + c0 + tx]);
    __syncthreads();
    out[(size_t)(c0 + ty) * 2048 + r0 + tx] = t[tx][ty];
}

// V inside QKV (b,s,4096 row: [Q2048|K1024|V1024]) -> Vt (b,kv,d,s)
__global__ __launch_bounds__(1024) void transpose_v(const u16* __restrict__ QKV,
                                                    u16* __restrict__ Vt) {
    __shared__ u16 t[32][33];
    const int tx = threadIdx.x, ty = threadIdx.y;
    const int b = blockIdx.z >> 3, kv = blockIdx.z & 7;
    const int s0 = blockIdx.x * 32, d0 = blockIdx.y * 32;
    t[ty][tx] = QKV[(size_t)(b * 2048 + s0 + ty) * 4096 + 3072 + kv * 128 + d0 + tx];
    __syncthreads();
    Vt[(size_t)((b * 8 + kv) * 128 + d0 + ty) * 2048 + s0 + tx] = t[tx][ty];
}

// ==========================================================================
// GEMM: C[M,N] = A[M,K] @ Bt[N,K]^T (bf16 in, fp32 acc, OUT_T out)
// tile 128x128, BK=64, 256 threads; global_load_lds width-16 staging (m97)
// ==========================================================================
template <typename OUT_T>
__global__ __launch_bounds__(256) void gemm_bt(const u16* __restrict__ A,
                                               const u16* __restrict__ Bt,
                                               OUT_T* __restrict__ C,
                                               int M, int N, int K) {
    __shared__ __align__(16) u16 As[128 * 64];
    __shared__ __align__(16) u16 Bs[128 * 64];
    const int tid = threadIdx.x;
    const int wave = tid >> 6, lane = tid & 63;
    const int lr = lane & 15, lq = lane >> 4;
    const int m0 = blockIdx.y * 128, n0 = blockIdx.x * 128;
    const int wr = (wave >> 1) * 64, wc = (wave & 1) * 64;

    floatx4 zf = {0.f, 0.f, 0.f, 0.f};
    floatx4 acc[4][4];
#pragma unroll
    for (int i = 0; i < 4; i++)
#pragma unroll
        for (int j = 0; j < 4; j++) acc[i][j] = zf;

    const int lrow = lane >> 3;          // 0..7 within chunk
    const int lcol = (lane & 7) << 3;    // 0..56

    for (int k0 = 0; k0 < K; k0 += 64) {
        __syncthreads();  // protect As/Bs from overwrite while previous iter reads
#pragma unroll
        for (int c = 0; c < 4; c++) {
            int chunk = (wave << 2) + c;          // 0..15
            int row = (chunk << 3) + lrow;        // 0..127
            __builtin_amdgcn_global_load_lds(
                (const AS1 void*)(A + (size_t)(m0 + row) * K + k0 + lcol),
                (AS3 void*)(As + (chunk << 9)), 16, 0, 0);
            __builtin_amdgcn_global_load_lds(
                (const AS1 void*)(Bt + (size_t)(n0 + row) * K + k0 + lcol),
                (AS3 void*)(Bs + (chunk << 9)), 16, 0, 0);
        }
        __syncthreads();  // vmcnt(0) drain makes staged data visible
#pragma unroll
        for (int kk = 0; kk < 64; kk += 32) {
            short8 af[4], bfr[4];
#pragma unroll
            for (int i = 0; i < 4; i++)
                af[i] = *(const short8*)(As + (wr + i * 16 + lr) * 64 + kk + lq * 8);
#pragma unroll
            for (int j = 0; j < 4; j++)
                bfr[j] = *(const short8*)(Bs + (wc + j * 16 + lr) * 64 + kk + lq * 8);
#pragma unroll
            for (int i = 0; i < 4; i++)
#pragma unroll
                for (int j = 0; j < 4; j++)
                    acc[i][j] = __builtin_amdgcn_mfma_f32_16x16x32_bf16(af[i], bfr[j], acc[i][j], 0, 0, 0);
        }
    }
#pragma unroll
    for (int i = 0; i < 4; i++)
#pragma unroll
        for (int j = 0; j < 4; j++)
#pragma unroll
            for (int r = 0; r < 4; r++) {
                int row = m0 + wr + i * 16 + lq * 4 + r;
                int col = n0 + wc + j * 16 + lr;
                if constexpr (sizeof(OUT_T) == 2)
                    C[(size_t)row * N + col] = f2bf(acc[i][j][r]);
                else
                    C[(size_t)row * N + col] = acc[i][j][r];
            }
}

// ==========================================================================
// RMS-norm + RoPE on Q/K inside QKV (row stride 4096), in place (bf16).
// One wave per 128-elem head row. Q also scaled by D^-0.5 * log2(e).
// ==========================================================================
__global__ __launch_bounds__(256) void norm_rope(u16* __restrict__ QKV,
                                                 const float* __restrict__ cosb,
                                                 const float* __restrict__ sinb,
                                                 const float* __restrict__ qw,
                                                 const float* __restrict__ kw) {
    const int tid = threadIdx.x;
    const int wave = tid >> 6, lane = tid & 63;
    const int t = blockIdx.x * 4 + wave;  // 0..98303
    u16* ptr;
    const float* w;
    float scale;
    int bs;
    if (t < 65536) {
        bs = t >> 4;
        ptr = QKV + (size_t)bs * 4096 + (t & 15) * 128;
        w = qw;
        scale = 0.08838834764831845f * 1.4426950408889634f;  // D^-0.5 * log2(e)
    } else {
        int t2 = t - 65536;
        bs = t2 >> 3;
        ptr = QKV + (size_t)bs * 4096 + 2048 + (t2 & 7) * 128;
        w = kw;
        scale = 1.0f;
    }
    const int d = lane * 2;
    u32 xv = *(const u32*)(ptr + d);
    float x0 = bf2f((u16)(xv & 0xffff)), x1 = bf2f((u16)(xv >> 16));
    float ss = x0 * x0 + x1 * x1;
#pragma unroll
    for (int off = 1; off < 64; off <<= 1) ss += __shfl_xor(ss, off);
    float rn = rsqrtf(ss * (1.0f / 128.0f) + 1e-6f);
    float2 wv = *(const float2*)(w + d);
    float y0 = x0 * rn * wv.x;
    float y1 = x1 * rn * wv.y;
    float p0 = __shfl_xor(y0, 32);
    float p1 = __shfl_xor(y1, 32);
    float sgn = (lane < 32) ? -1.0f : 1.0f;
    float2 cv = *(const float2*)(cosb + (size_t)bs * 128 + d);
    float2 sv = *(const float2*)(sinb + (size_t)bs * 128 + d);
    float o0 = (y0 * cv.x + sgn * p0 * sv.x) * scale;
    float o1 = (y1 * cv.y + sgn * p1 * sv.y) * scale;
    *(u32*)(ptr + d) = (u32)f2bf(o0) | ((u32)f2bf(o1) << 16);
}

// ==========================================================================
// Causal GQA flash attention, transposed-score formulation.
// Double-buffered async staging: global_load_lds(16B) -> Ks/Vs[2], one
// __syncthreads per iter; tile kt+1 flies during tile kt's compute (in-flight
// state lives in the vmcnt queue, not VGPRs -> no spill).
// XOR-swizzled LDS (chunk16 ^= row&15 / row&7): conflict-free without padding,
// keeping global_load_lds's lane-contiguous LDS destination legal.
// LDS = 2*16K + 2*16K + 16K = 81920 B = exactly 2 blocks/CU.
// grid (S/128, NH, B), 512 thr = 8 waves x 16 q-rows; key tile 64.
// ==========================================================================
__global__ __launch_bounds__(512, 2) void attn_kernel(const u16* __restrict__ QKV,
                                                      const u16* __restrict__ Vt,
                                                      u16* __restrict__ O) {
    __shared__ __align__(16) u16 Ks[2][64 * 128];   // [key][d]   swizzled
    __shared__ __align__(16) u16 Vs[2][128 * 64];   // [d][key]   swizzled
    __shared__ __align__(16) u16 Ps[128 * 64];      // [qrow][key] swizzled
    const int tid = threadIdx.x;
    const int wave = tid >> 6, lane = tid & 63;
    const int lr = lane & 15, lq = lane >> 4;
    const int qt = 15 - blockIdx.x;  // heavy tiles dispatch first
    const int h = blockIdx.y, b = blockIdx.z;
    const int kv = h >> 1;
    const int q0 = qt * 128;
    const int wq = wave * 16;

    // async stage of one 64-key tile into buffer `buf` (4 instrs/wave)
    auto stage = [&](int buf, int k0s) {
#pragma unroll
        for (int j = 0; j < 2; j++) {   // Ks: 64 rows x 256 B
            int r = wave * 8 + j * 4 + (lane >> 4);
            int c = (lane & 15) ^ (r & 15);   // global chunk for this lane's slot
            __builtin_amdgcn_global_load_lds(
                (const AS1 void*)(QKV + (size_t)(b * 2048 + k0s + r) * 4096 + 2048 + kv * 128 + c * 8),
                (AS3 void*)(&Ks[buf][(wave * 8 + j * 4) * 128]), 16, 0, 0);
        }
#pragma unroll
        for (int j = 0; j < 2; j++) {   // Vs: 128 rows x 128 B
            int r = wave * 16 + j * 8 + (lane >> 3);
            int c = (lane & 7) ^ (r & 7);
            __builtin_amdgcn_global_load_lds(
                (const AS1 void*)(Vt + (size_t)((b * 8 + kv) * 128 + r) * 2048 + k0s + c * 8),
                (AS3 void*)(&Vs[buf][(wave * 16 + j * 8) * 64]), 16, 0, 0);
        }
    };

    // Q fragments in registers (B-operand: n=qrow on lr, k=d on lq*8+j)
    short8 qf[4];
#pragma unroll
    for (int t = 0; t < 4; t++)
        qf[t] = *(const short8*)(QKV + (size_t)(b * 2048 + q0 + wq + lr) * 4096 + h * 128 + t * 32 + lq * 8);

    floatx4 zf = {0.f, 0.f, 0.f, 0.f};
    floatx4 oacc[8];
#pragma unroll
    for (int jn = 0; jn < 8; jn++) oacc[jn] = zf;
    float mstate = -1e30f;
    float lstate = 0.f;

    const int nIter = (qt + 1) * 2;

    stage(0, 0);  // prologue: tile 0 -> buffer 0

    for (int kt = 0; kt < nIter; kt++) {
        const int k0 = kt * 64;
        const int cur = kt & 1;
        // (a) all waves done reading buf[cur^1]; (b) vmcnt drain -> tile kt
        // committed to buf[cur]. Loads for kt+1 (issued below) had the whole
        // previous compute phase in flight.
        __syncthreads();
        if (kt + 1 < nIter) stage(cur ^ 1, k0 + 64);

        // wave-level causal skip: this wave's 16 q-rows all < k0 -> zero tile
        if (k0 <= q0 + wq + 15) {
            const u16* KsC = &Ks[cur][0];
            const u16* VsC = &Vs[cur][0];
            // S^T = K @ Q^T : sacc[jm]; key = jm*16+lq*4+r, qrow = lr
            floatx4 sacc[4];
#pragma unroll
            for (int jm = 0; jm < 4; jm++) sacc[jm] = zf;
#pragma unroll
            for (int t = 0; t < 4; t++) {
                short8 a[4];
#pragma unroll
                for (int jm = 0; jm < 4; jm++)
                    a[jm] = *(const short8*)(KsC + (jm * 16 + lr) * 128 + (((t * 4 + lq) ^ lr) << 3));
#pragma unroll
                for (int jm = 0; jm < 4; jm++)
                    sacc[jm] = __builtin_amdgcn_mfma_f32_16x16x32_bf16(a[jm], qf[t], sacc[jm], 0, 0, 0);
            }

            // causal mask (wave-uniform branch)
            if (k0 + 63 > q0 + wq) {
#pragma unroll
                for (int jm = 0; jm < 4; jm++) {
                    int diff = (q0 + wq + lr) - (k0 + jm * 16 + lq * 4);
#pragma unroll
                    for (int r = 0; r < 4; r++)
                        if (r > diff) sacc[jm][r] = -1e30f;
                }
            }

            // online softmax per qrow (qrow on lane&15; reduce across quads)
            float mx = -1e30f;
#pragma unroll
            for (int jm = 0; jm < 4; jm++)
#pragma unroll
                for (int r = 0; r < 4; r++) mx = fmaxf(mx, sacc[jm][r]);
            mx = fmaxf(mx, __shfl_xor(mx, 16));
            mx = fmaxf(mx, __shfl_xor(mx, 32));
            float mnew = fmaxf(mstate, mx);
            float alpha = exp2f(mstate - mnew);
            mstate = mnew;
            float rs = 0.f;
#pragma unroll
            for (int jm = 0; jm < 4; jm++)
#pragma unroll
                for (int r = 0; r < 4; r++) {
                    float p = exp2f(sacc[jm][r] - mnew);
                    sacc[jm][r] = p;
                    rs += p;
                }
            rs += __shfl_xor(rs, 16);
            rs += __shfl_xor(rs, 32);
            lstate = lstate * alpha + rs;

            // P^T -> Ps (swizzled): lane packs 4 consecutive keys = 8B write.
            // Ps rows wq..wq+15 are written AND read only by this wave.
#pragma unroll
            for (int jm = 0; jm < 4; jm++) {
                u16 o[4] = {f2bf(sacc[jm][0]), f2bf(sacc[jm][1]),
                            f2bf(sacc[jm][2]), f2bf(sacc[jm][3])};
                int p = ((jm << 1) + (lq >> 1)) ^ (lr & 7);   // chunk16 swizzle
                *(u64*)(Ps + (wq + lr) * 64 + p * 8 + (lq & 1) * 4) = *(u64*)o;
            }

            // rescale O: alpha at qrow=lr; oacc rows at qrow=lq*4+r
            float ao[4];
#pragma unroll
            for (int r = 0; r < 4; r++) ao[r] = __shfl(alpha, lq * 4 + r);
#pragma unroll
            for (int jn = 0; jn < 8; jn++)
#pragma unroll
                for (int r = 0; r < 4; r++) oacc[jn][r] *= ao[r];

            // O += P @ V (A=P own rows, B=V d-rows; both b128, swizzled)
#pragma unroll
            for (int t = 0; t < 2; t++) {
                short8 pa, vb[8];
                pa = *(const short8*)(Ps + (wq + lr) * 64 + (((t * 4 + lq) ^ (lr & 7)) << 3));
#pragma unroll
                for (int jn = 0; jn < 8; jn++)
                    vb[jn] = *(const short8*)(VsC + (jn * 16 + lr) * 64 + (((t * 4 + lq) ^ (lr & 7)) << 3));
#pragma unroll
                for (int jn = 0; jn < 8; jn++)
                    oacc[jn] = __builtin_amdgcn_mfma_f32_16x16x32_bf16(pa, vb[jn], oacc[jn], 0, 0, 0);
            }
        }
    }

    // epilogue: O / l   (l at qrow=lr -> transpose to qrow=lq*4+r)
    float lo[4];
#pragma unroll
    for (int r = 0; r < 4; r++) lo[r] = __shfl(lstate, lq * 4 + r);
#pragma unroll
    for (int jn = 0; jn < 8; jn++)
#pragma unroll
        for (int r = 0; r < 4; r++) {
            int row = q0 + wq + lq * 4 + r;
            O[(size_t)(b * 2048 + row) * 2048 + h * 128 + jn * 16 + lr] =
                f2bf(oacc[jn][r] / lo[r]);
        }
}

// ==========================================================================
extern "C" void kernel_launch(void* const* d_in, const int* in_sizes, int n_in,
                              void* d_out, int out_size, void* d_ws, size_t ws_size,
                              hipStream_t stream) {
    const float* X = (const float*)d_in[0];
    const float* cosb = (const float*)d_in[1];
    const float* sinb = (const float*)d_in[2];
    const float* Wq = (const float*)d_in[3];
    const float* Wk = (const float*)d_in[4];
    const float* Wv = (const float*)d_in[5];
    const float* Wo = (const float*)d_in[6];
    const float* qw = (const float*)d_in[7];
    const float* kw = (const float*)d_in[8];
    float* out = (float*)d_out;
    u16* ws = (u16*)d_ws;

    u16* WqkvT = ws;                    // 4096x2048 = 8388608
    u16* WoT = WqkvT + 8388608;         // 4194304
    u16* Xb = WoT + 4194304;            // 8388608 (dead after QKV GEMM)
    u16* QKVb = Xb + 8388608;           // 4096x4096 = 16777216
    u16* Vtb = QKVb + 16777216;         // 4194304
    u16* Ob = Xb;                       // alias
    // total 41,943,040 u16 = 83.9 MB

    dim3 tb(32, 32);
    transpose_wall<<<dim3(64, 64, 4), tb, 0, stream>>>(Wq, Wk, Wv, Wo, WqkvT, WoT);
    convert_x<<<8192, 256, 0, stream>>>(X, Xb);

    gemm_bt<u16><<<dim3(32, 32), 256, 0, stream>>>(Xb, WqkvT, QKVb, 4096, 4096, 2048);

    norm_rope<<<24576, 256, 0, stream>>>(QKVb, cosb, sinb, qw, kw);
    transpose_v<<<dim3(64, 4, 16), tb, 0, stream>>>(QKVb, Vtb);

    attn_kernel<<<dim3(16, 16, 2), 512, 0, stream>>>(QKVb, Vtb, Ob);

    gemm_bt<float><<<dim3(16, 32), 256, 0, stream>>>(Ob, WoT, out, 4096, 2048, 2048);
}

// Round 8
// 442.672 us; speedup vs baseline: 1.1191x; 1.0311x over previous
//
#include <hip/hip_runtime.h>

typedef unsigned short u16;
typedef unsigned int u32;
typedef unsigned long long u64;
typedef __attribute__((ext_vector_type(8))) short short8;
typedef __attribute__((ext_vector_type(4))) float floatx4;

#define AS1 __attribute__((address_space(1)))
#define AS3 __attribute__((address_space(3)))

// ---- bf16 <-> f32 helpers (raw bits, RNE) ----
__device__ __forceinline__ float bf2f(u16 u) {
    u32 x = ((u32)u) << 16;
    float f;
    __builtin_memcpy(&f, &x, 4);
    return f;
}
__device__ __forceinline__ u16 f2bf(float f) {
    u32 x;
    __builtin_memcpy(&x, &f, 4);
    u32 r = (x + 0x7fffu + ((x >> 16) & 1u)) >> 16;
    return (u16)r;
}

// ==========================================================================
// Convert f32 -> bf16, 4 elems/thread
// ==========================================================================
__global__ __launch_bounds__(256) void convert_x(const float* __restrict__ in,
                                                 u16* __restrict__ out) {
    int i = blockIdx.x * 256 + threadIdx.x;
    float4 v = *(const float4*)(in + (size_t)i * 4);
    u16 o[4] = {f2bf(v.x), f2bf(v.y), f2bf(v.z), f2bf(v.w)};
    *(u64*)(out + (size_t)i * 4) = *(u64*)o;
}

// ==========================================================================
// All four weight transposes in one launch (z selects matrix).
// in f32 (R x C) -> out bf16 (C x R); R=2048 for all.
// ==========================================================================
__global__ __launch_bounds__(1024) void transpose_wall(const float* __restrict__ Wq,
                                                       const float* __restrict__ Wk,
                                                       const float* __restrict__ Wv,
                                                       const float* __restrict__ Wo,
                                                       u16* __restrict__ WqkvT,
                                                       u16* __restrict__ WoT) {
    const int z = blockIdx.z;
    const float* in;
    u16* out;
    int C;
    if (z == 0) { in = Wq; out = WqkvT; C = 2048; }
    else if (z == 1) { in = Wk; out = WqkvT + 2048 * 2048; C = 1024; }
    else if (z == 2) { in = Wv; out = WqkvT + 3072 * 2048; C = 1024; }
    else { in = Wo; out = WoT; C = 2048; }
    const int c0 = blockIdx.x * 32, r0 = blockIdx.y * 32;
    if (c0 >= C) return;
    __shared__ u16 t[32][33];
    const int tx = threadIdx.x, ty = threadIdx.y;
    t[ty][tx] = f2bf(in[(size_t)(r0 + ty) * C + c0 + tx]);
    __syncthreads();
    out[(size_t)(c0 + ty) * 2048 + r0 + tx] = t[tx][ty];
}

// V inside QKV (b,s,4096 row: [Q2048|K1024|V1024]) -> Vt (b,kv,d,s)
__global__ __launch_bounds__(1024) void transpose_v(const u16* __restrict__ QKV,
                                                    u16* __restrict__ Vt) {
    __shared__ u16 t[32][33];
    const int tx = threadIdx.x, ty = threadIdx.y;
    const int b = blockIdx.z >> 3, kv = blockIdx.z & 7;
    const int s0 = blockIdx.x * 32, d0 = blockIdx.y * 32;
    t[ty][tx] = QKV[(size_t)(b * 2048 + s0 + ty) * 4096 + 3072 + kv * 128 + d0 + tx];
    __syncthreads();
    Vt[(size_t)((b * 8 + kv) * 128 + d0 + ty) * 2048 + s0 + tx] = t[tx][ty];
}

// ==========================================================================
// GEMM: C[M,N] = A[M,K] @ Bt[N,K]^T (bf16 in, fp32 acc, OUT_T out)
// tile 128x128, BK=64, 256 threads; global_load_lds width-16 staging (m97)
// ==========================================================================
template <typename OUT_T>
__global__ __launch_bounds__(256) void gemm_bt(const u16* __restrict__ A,
                                               const u16* __restrict__ Bt,
                                               OUT_T* __restrict__ C,
                                               int M, int N, int K) {
    __shared__ __align__(16) u16 As[128 * 64];
    __shared__ __align__(16) u16 Bs[128 * 64];
    const int tid = threadIdx.x;
    const int wave = tid >> 6, lane = tid & 63;
    const int lr = lane & 15, lq = lane >> 4;
    const int m0 = blockIdx.y * 128, n0 = blockIdx.x * 128;
    const int wr = (wave >> 1) * 64, wc = (wave & 1) * 64;

    floatx4 zf = {0.f, 0.f, 0.f, 0.f};
    floatx4 acc[4][4];
#pragma unroll
    for (int i = 0; i < 4; i++)
#pragma unroll
        for (int j = 0; j < 4; j++) acc[i][j] = zf;

    const int lrow = lane >> 3;          // 0..7 within chunk
    const int lcol = (lane & 7) << 3;    // 0..56

    for (int k0 = 0; k0 < K; k0 += 64) {
        __syncthreads();  // protect As/Bs from overwrite while previous iter reads
#pragma unroll
        for (int c = 0; c < 4; c++) {
            int chunk = (wave << 2) + c;          // 0..15
            int row = (chunk << 3) + lrow;        // 0..127
            __builtin_amdgcn_global_load_lds(
                (const AS1 void*)(A + (size_t)(m0 + row) * K + k0 + lcol),
                (AS3 void*)(As + (chunk << 9)), 16, 0, 0);
            __builtin_amdgcn_global_load_lds(
                (const AS1 void*)(Bt + (size_t)(n0 + row) * K + k0 + lcol),
                (AS3 void*)(Bs + (chunk << 9)), 16, 0, 0);
        }
        __syncthreads();  // vmcnt(0) drain makes staged data visible
#pragma unroll
        for (int kk = 0; kk < 64; kk += 32) {
            short8 af[4], bfr[4];
#pragma unroll
            for (int i = 0; i < 4; i++)
                af[i] = *(const short8*)(As + (wr + i * 16 + lr) * 64 + kk + lq * 8);
#pragma unroll
            for (int j = 0; j < 4; j++)
                bfr[j] = *(const short8*)(Bs + (wc + j * 16 + lr) * 64 + kk + lq * 8);
#pragma unroll
            for (int i = 0; i < 4; i++)
#pragma unroll
                for (int j = 0; j < 4; j++)
                    acc[i][j] = __builtin_amdgcn_mfma_f32_16x16x32_bf16(af[i], bfr[j], acc[i][j], 0, 0, 0);
        }
    }
#pragma unroll
    for (int i = 0; i < 4; i++)
#pragma unroll
        for (int j = 0; j < 4; j++)
#pragma unroll
            for (int r = 0; r < 4; r++) {
                int row = m0 + wr + i * 16 + lq * 4 + r;
                int col = n0 + wc + j * 16 + lr;
                if constexpr (sizeof(OUT_T) == 2)
                    C[(size_t)row * N + col] = f2bf(acc[i][j][r]);
                else
                    C[(size_t)row * N + col] = acc[i][j][r];
            }
}

// ==========================================================================
// RMS-norm + RoPE on Q/K inside QKV (row stride 4096), in place (bf16).
// One wave per 128-elem head row. Q also scaled by D^-0.5 * log2(e).
// ==========================================================================
__global__ __launch_bounds__(256) void norm_rope(u16* __restrict__ QKV,
                                                 const float* __restrict__ cosb,
                                                 const float* __restrict__ sinb,
                                                 const float* __restrict__ qw,
                                                 const float* __restrict__ kw) {
    const int tid = threadIdx.x;
    const int wave = tid >> 6, lane = tid & 63;
    const int t = blockIdx.x * 4 + wave;  // 0..98303
    u16* ptr;
    const float* w;
    float scale;
    int bs;
    if (t < 65536) {
        bs = t >> 4;
        ptr = QKV + (size_t)bs * 4096 + (t & 15) * 128;
        w = qw;
        scale = 0.08838834764831845f * 1.4426950408889634f;  // D^-0.5 * log2(e)
    } else {
        int t2 = t - 65536;
        bs = t2 >> 3;
        ptr = QKV + (size_t)bs * 4096 + 2048 + (t2 & 7) * 128;
        w = kw;
        scale = 1.0f;
    }
    const int d = lane * 2;
    u32 xv = *(const u32*)(ptr + d);
    float x0 = bf2f((u16)(xv & 0xffff)), x1 = bf2f((u16)(xv >> 16));
    float ss = x0 * x0 + x1 * x1;
#pragma unroll
    for (int off = 1; off < 64; off <<= 1) ss += __shfl_xor(ss, off);
    float rn = rsqrtf(ss * (1.0f / 128.0f) + 1e-6f);
    float2 wv = *(const float2*)(w + d);
    float y0 = x0 * rn * wv.x;
    float y1 = x1 * rn * wv.y;
    float p0 = __shfl_xor(y0, 32);
    float p1 = __shfl_xor(y1, 32);
    float sgn = (lane < 32) ? -1.0f : 1.0f;
    float2 cv = *(const float2*)(cosb + (size_t)bs * 128 + d);
    float2 sv = *(const float2*)(sinb + (size_t)bs * 128 + d);
    float o0 = (y0 * cv.x + sgn * p0 * sv.x) * scale;
    float o1 = (y1 * cv.y + sgn * p1 * sv.y) * scale;
    *(u32*)(ptr + d) = (u32)f2bf(o0) | ((u32)f2bf(o1) << 16);
}

// ==========================================================================
// Causal GQA flash attention, transposed-score formulation.
// Double-buffered async global_load_lds staging (in-flight state in the
// vmcnt queue, not VGPRs); XOR-swizzled LDS (conflict-free, unpadded).
// P never touches LDS: the PV MFMA uses a permuted k-order
//   pi(lq*8+j) = 32t + (j>>2)*16 + 4lq + (j&3)
// applied identically to the P (A) and V (B) fragments, so the softmax
// output registers feed MFMA directly. LDS = 2*16K(Ks) + 2*16K(Vs) = 64 KB
// -> 2 blocks/CU. grid (S/128, NH, B), 512 thr = 8 waves x 16 q-rows.
// ==========================================================================
__global__ __launch_bounds__(512, 2) void attn_kernel(const u16* __restrict__ QKV,
                                                      const u16* __restrict__ Vt,
                                                      u16* __restrict__ O) {
    __shared__ __align__(16) u16 Ks[2][64 * 128];   // [key][d]   swizzled
    __shared__ __align__(16) u16 Vs[2][128 * 64];   // [d][key]   swizzled
    const int tid = threadIdx.x;
    const int wave = tid >> 6, lane = tid & 63;
    const int lr = lane & 15, lq = lane >> 4;
    const int qt = 15 - blockIdx.x;  // heavy tiles dispatch first
    const int h = blockIdx.y, b = blockIdx.z;
    const int kv = h >> 1;
    const int q0 = qt * 128;
    const int wq = wave * 16;

    // async stage of one 64-key tile into buffer `buf` (4 instrs/wave)
    auto stage = [&](int buf, int k0s) {
#pragma unroll
        for (int j = 0; j < 2; j++) {   // Ks: 64 rows x 256 B
            int r = wave * 8 + j * 4 + (lane >> 4);
            int c = (lane & 15) ^ (r & 15);   // global chunk for this lane's slot
            __builtin_amdgcn_global_load_lds(
                (const AS1 void*)(QKV + (size_t)(b * 2048 + k0s + r) * 4096 + 2048 + kv * 128 + c * 8),
                (AS3 void*)(&Ks[buf][(wave * 8 + j * 4) * 128]), 16, 0, 0);
        }
#pragma unroll
        for (int j = 0; j < 2; j++) {   // Vs: 128 rows x 128 B
            int r = wave * 16 + j * 8 + (lane >> 3);
            int c = (lane & 7) ^ (r & 7);
            __builtin_amdgcn_global_load_lds(
                (const AS1 void*)(Vt + (size_t)((b * 8 + kv) * 128 + r) * 2048 + k0s + c * 8),
                (AS3 void*)(&Vs[buf][(wave * 16 + j * 8) * 64]), 16, 0, 0);
        }
    };

    // Q fragments in registers (B-operand: n=qrow on lr, k=d on lq*8+j)
    short8 qf[4];
#pragma unroll
    for (int t = 0; t < 4; t++)
        qf[t] = *(const short8*)(QKV + (size_t)(b * 2048 + q0 + wq + lr) * 4096 + h * 128 + t * 32 + lq * 8);

    floatx4 zf = {0.f, 0.f, 0.f, 0.f};
    floatx4 oacc[8];
#pragma unroll
    for (int jn = 0; jn < 8; jn++) oacc[jn] = zf;
    float mstate = -1e30f;
    float lstate = 0.f;

    const int nIter = (qt + 1) * 2;

    stage(0, 0);  // prologue: tile 0 -> buffer 0

    for (int kt = 0; kt < nIter; kt++) {
        const int k0 = kt * 64;
        const int cur = kt & 1;
        // (a) all waves done reading buf[cur^1]; (b) vmcnt drain -> tile kt
        // committed to buf[cur]. Loads for kt+1 (issued below) stay in
        // flight across the whole compute phase.
        __syncthreads();
        if (kt + 1 < nIter) stage(cur ^ 1, k0 + 64);

        // wave-level causal skip: this wave's 16 q-rows all < k0 -> zero tile
        if (k0 <= q0 + wq + 15) {
            const u16* KsC = &Ks[cur][0];
            const u16* VsC = &Vs[cur][0];
            // S^T = K @ Q^T : sacc[jm]; key = jm*16+lq*4+r, qrow = lr
            floatx4 sacc[4];
#pragma unroll
            for (int jm = 0; jm < 4; jm++) sacc[jm] = zf;
#pragma unroll
            for (int t = 0; t < 4; t++) {
                short8 a[4];
#pragma unroll
                for (int jm = 0; jm < 4; jm++)
                    a[jm] = *(const short8*)(KsC + (jm * 16 + lr) * 128 + (((t * 4 + lq) ^ lr) << 3));
#pragma unroll
                for (int jm = 0; jm < 4; jm++)
                    sacc[jm] = __builtin_amdgcn_mfma_f32_16x16x32_bf16(a[jm], qf[t], sacc[jm], 0, 0, 0);
            }

            // causal mask (wave-uniform branch)
            if (k0 + 63 > q0 + wq) {
#pragma unroll
                for (int jm = 0; jm < 4; jm++) {
                    int diff = (q0 + wq + lr) - (k0 + jm * 16 + lq * 4);
#pragma unroll
                    for (int r = 0; r < 4; r++)
                        if (r > diff) sacc[jm][r] = -1e30f;
                }
            }

            // online softmax per qrow (qrow on lane&15; reduce across quads)
            float mx = -1e30f;
#pragma unroll
            for (int jm = 0; jm < 4; jm++)
#pragma unroll
                for (int r = 0; r < 4; r++) mx = fmaxf(mx, sacc[jm][r]);
            mx = fmaxf(mx, __shfl_xor(mx, 16));
            mx = fmaxf(mx, __shfl_xor(mx, 32));
            float mnew = fmaxf(mstate, mx);
            float alpha = exp2f(mstate - mnew);
            mstate = mnew;
            float rs = 0.f;
#pragma unroll
            for (int jm = 0; jm < 4; jm++)
#pragma unroll
                for (int r = 0; r < 4; r++) {
                    float p = exp2f(sacc[jm][r] - mnew);
                    sacc[jm][r] = p;
                    rs += p;
                }
            rs += __shfl_xor(rs, 16);
            rs += __shfl_xor(rs, 32);
            lstate = lstate * alpha + rs;

            // pack P to bf16 in-register: pb[jm] = keys jm*16+4lq+0..3, qrow=lr
            u64 pb[4];
#pragma unroll
            for (int jm = 0; jm < 4; jm++) {
                u16 o[4] = {f2bf(sacc[jm][0]), f2bf(sacc[jm][1]),
                            f2bf(sacc[jm][2]), f2bf(sacc[jm][3])};
                pb[jm] = *(u64*)o;
            }

            // rescale O: alpha at qrow=lr; oacc rows at qrow=lq*4+r
            float ao[4];
#pragma unroll
            for (int r = 0; r < 4; r++) ao[r] = __shfl(alpha, lq * 4 + r);
#pragma unroll
            for (int jn = 0; jn < 8; jn++)
#pragma unroll
                for (int r = 0; r < 4; r++) oacc[jn][r] *= ao[r];

            // O += P @ V, permuted k-order; A-frag straight from registers,
            // B-frag = V at the same permuted keys (two 8B LDS reads each).
#pragma unroll
            for (int t = 0; t < 2; t++) {
                union { short8 v; u64 q[2]; } pa;
                pa.q[0] = pb[2 * t];
                pa.q[1] = pb[2 * t + 1];
#pragma unroll
                for (int jn = 0; jn < 8; jn++) {
                    const u16* vrow = VsC + (jn * 16 + lr) * 64 + (lq & 1) * 4;
                    union { short8 v; u64 q[2]; } vb;
                    vb.q[0] = *(const u64*)(vrow + (((t * 4 + (lq >> 1)) ^ (lr & 7)) << 3));
                    vb.q[1] = *(const u64*)(vrow + (((t * 4 + 2 + (lq >> 1)) ^ (lr & 7)) << 3));
                    oacc[jn] = __builtin_amdgcn_mfma_f32_16x16x32_bf16(pa.v, vb.v, oacc[jn], 0, 0, 0);
                }
            }
        }
    }

    // epilogue: O / l   (l at qrow=lr -> transpose to qrow=lq*4+r)
    float lo[4];
#pragma unroll
    for (int r = 0; r < 4; r++) lo[r] = __shfl(lstate, lq * 4 + r);
#pragma unroll
    for (int jn = 0; jn < 8; jn++)
#pragma unroll
        for (int r = 0; r < 4; r++) {
            int row = q0 + wq + lq * 4 + r;
            O[(size_t)(b * 2048 + row) * 2048 + h * 128 + jn * 16 + lr] =
                f2bf(oacc[jn][r] / lo[r]);
        }
}

// ==========================================================================
extern "C" void kernel_launch(void* const* d_in, const int* in_sizes, int n_in,
                              void* d_out, int out_size, void* d_ws, size_t ws_size,
                              hipStream_t stream) {
    const float* X = (const float*)d_in[0];
    const float* cosb = (const float*)d_in[1];
    const float* sinb = (const float*)d_in[2];
    const float* Wq = (const float*)d_in[3];
    const float* Wk = (const float*)d_in[4];
    const float* Wv = (const float*)d_in[5];
    const float* Wo = (const float*)d_in[6];
    const float* qw = (const float*)d_in[7];
    const float* kw = (const float*)d_in[8];
    float* out = (float*)d_out;
    u16* ws = (u16*)d_ws;

    u16* WqkvT = ws;                    // 4096x2048 = 8388608
    u16* WoT = WqkvT + 8388608;         // 4194304
    u16* Xb = WoT + 4194304;            // 8388608 (dead after QKV GEMM)
    u16* QKVb = Xb + 8388608;           // 4096x4096 = 16777216
    u16* Vtb = QKVb + 16777216;         // 4194304
    u16* Ob = Xb;                       // alias
    // total 41,943,040 u16 = 83.9 MB

    dim3 tb(32, 32);
    transpose_wall<<<dim3(64, 64, 4), tb, 0, stream>>>(Wq, Wk, Wv, Wo, WqkvT, WoT);
    convert_x<<<8192, 256, 0, stream>>>(X, Xb);

    gemm_bt<u16><<<dim3(32, 32), 256, 0, stream>>>(Xb, WqkvT, QKVb, 4096, 4096, 2048);

    norm_rope<<<24576, 256, 0, stream>>>(QKVb, cosb, sinb, qw, kw);
    transpose_v<<<dim3(64, 4, 16), tb, 0, stream>>>(QKVb, Vtb);

    attn_kernel<<<dim3(16, 16, 2), 512, 0, stream>>>(QKVb, Vtb, Ob);

    gemm_bt<float><<<dim3(16, 32), 256, 0, stream>>>(Ob, WoT, out, 4096, 2048, 2048);
}

// Round 9
// 404.891 us; speedup vs baseline: 1.2235x; 1.0933x over previous
//
#include <hip/hip_runtime.h>
#include <hip/hip_bf16.h>

typedef unsigned short u16;
typedef unsigned int u32;
typedef unsigned long long u64;
typedef __attribute__((ext_vector_type(8))) short short8;
typedef __attribute__((ext_vector_type(4))) float floatx4;

#define AS1 __attribute__((address_space(1)))
#define AS3 __attribute__((address_space(3)))

// ---- bf16 <-> f32 helpers (raw bits, RNE) ----
__device__ __forceinline__ float bf2f(u16 u) {
    u32 x = ((u32)u) << 16;
    float f;
    __builtin_memcpy(&f, &x, 4);
    return f;
}
__device__ __forceinline__ u16 f2bf(float f) {
    u32 x;
    __builtin_memcpy(&x, &f, 4);
    u32 r = (x + 0x7fffu + ((x >> 16) & 1u)) >> 16;
    return (u16)r;
}
// packed 2xf32 -> 2xbf16 (v_cvt_pk_bf16_f32), returned as u32 (lo=first)
__device__ __forceinline__ u32 f2bf_pk(float a, float b) {
    __hip_bfloat162 h = __float22bfloat162_rn(float2{a, b});
    u32 r;
    __builtin_memcpy(&r, &h, 4);
    return r;
}

// ==========================================================================
// Convert f32 -> bf16, 4 elems/thread
// ==========================================================================
__global__ __launch_bounds__(256) void convert_x(const float* __restrict__ in,
                                                 u16* __restrict__ out) {
    int i = blockIdx.x * 256 + threadIdx.x;
    float4 v = *(const float4*)(in + (size_t)i * 4);
    u16 o[4] = {f2bf(v.x), f2bf(v.y), f2bf(v.z), f2bf(v.w)};
    *(u64*)(out + (size_t)i * 4) = *(u64*)o;
}

// ==========================================================================
// All four weight transposes in one launch (z selects matrix).
// in f32 (R x C) -> out bf16 (C x R); R=2048 for all.
// ==========================================================================
__global__ __launch_bounds__(1024) void transpose_wall(const float* __restrict__ Wq,
                                                       const float* __restrict__ Wk,
                                                       const float* __restrict__ Wv,
                                                       const float* __restrict__ Wo,
                                                       u16* __restrict__ WqkvT,
                                                       u16* __restrict__ WoT) {
    const int z = blockIdx.z;
    const float* in;
    u16* out;
    int C;
    if (z == 0) { in = Wq; out = WqkvT; C = 2048; }
    else if (z == 1) { in = Wk; out = WqkvT + 2048 * 2048; C = 1024; }
    else if (z == 2) { in = Wv; out = WqkvT + 3072 * 2048; C = 1024; }
    else { in = Wo; out = WoT; C = 2048; }
    const int c0 = blockIdx.x * 32, r0 = blockIdx.y * 32;
    if (c0 >= C) return;
    __shared__ u16 t[32][33];
    const int tx = threadIdx.x, ty = threadIdx.y;
    t[ty][tx] = f2bf(in[(size_t)(r0 + ty) * C + c0 + tx]);
    __syncthreads();
    out[(size_t)(c0 + ty) * 2048 + r0 + tx] = t[tx][ty];
}

// V inside QKV (b,s,4096 row: [Q2048|K1024|V1024]) -> Vt (b,kv,d,s)
__global__ __launch_bounds__(1024) void transpose_v(const u16* __restrict__ QKV,
                                                    u16* __restrict__ Vt) {
    __shared__ u16 t[32][33];
    const int tx = threadIdx.x, ty = threadIdx.y;
    const int b = blockIdx.z >> 3, kv = blockIdx.z & 7;
    const int s0 = blockIdx.x * 32, d0 = blockIdx.y * 32;
    t[ty][tx] = QKV[(size_t)(b * 2048 + s0 + ty) * 4096 + 3072 + kv * 128 + d0 + tx];
    __syncthreads();
    Vt[(size_t)((b * 8 + kv) * 128 + d0 + ty) * 2048 + s0 + tx] = t[tx][ty];
}

// ==========================================================================
// GEMM: C[M,N] = A[M,K] @ Bt[N,K]^T (bf16 in, fp32 acc, OUT_T out)
// tile 128x128, BK=64, 256 threads; global_load_lds width-16 staging (m97)
// ==========================================================================
template <typename OUT_T>
__global__ __launch_bounds__(256) void gemm_bt(const u16* __restrict__ A,
                                               const u16* __restrict__ Bt,
                                               OUT_T* __restrict__ C,
                                               int M, int N, int K) {
    __shared__ __align__(16) u16 As[128 * 64];
    __shared__ __align__(16) u16 Bs[128 * 64];
    const int tid = threadIdx.x;
    const int wave = tid >> 6, lane = tid & 63;
    const int lr = lane & 15, lq = lane >> 4;
    const int m0 = blockIdx.y * 128, n0 = blockIdx.x * 128;
    const int wr = (wave >> 1) * 64, wc = (wave & 1) * 64;

    floatx4 zf = {0.f, 0.f, 0.f, 0.f};
    floatx4 acc[4][4];
#pragma unroll
    for (int i = 0; i < 4; i++)
#pragma unroll
        for (int j = 0; j < 4; j++) acc[i][j] = zf;

    const int lrow = lane >> 3;          // 0..7 within chunk
    const int lcol = (lane & 7) << 3;    // 0..56

    for (int k0 = 0; k0 < K; k0 += 64) {
        __syncthreads();  // protect As/Bs from overwrite while previous iter reads
#pragma unroll
        for (int c = 0; c < 4; c++) {
            int chunk = (wave << 2) + c;          // 0..15
            int row = (chunk << 3) + lrow;        // 0..127
            __builtin_amdgcn_global_load_lds(
                (const AS1 void*)(A + (size_t)(m0 + row) * K + k0 + lcol),
                (AS3 void*)(As + (chunk << 9)), 16, 0, 0);
            __builtin_amdgcn_global_load_lds(
                (const AS1 void*)(Bt + (size_t)(n0 + row) * K + k0 + lcol),
                (AS3 void*)(Bs + (chunk << 9)), 16, 0, 0);
        }
        __syncthreads();  // vmcnt(0) drain makes staged data visible
#pragma unroll
        for (int kk = 0; kk < 64; kk += 32) {
            short8 af[4], bfr[4];
#pragma unroll
            for (int i = 0; i < 4; i++)
                af[i] = *(const short8*)(As + (wr + i * 16 + lr) * 64 + kk + lq * 8);
#pragma unroll
            for (int j = 0; j < 4; j++)
                bfr[j] = *(const short8*)(Bs + (wc + j * 16 + lr) * 64 + kk + lq * 8);
#pragma unroll
            for (int i = 0; i < 4; i++)
#pragma unroll
                for (int j = 0; j < 4; j++)
                    acc[i][j] = __builtin_amdgcn_mfma_f32_16x16x32_bf16(af[i], bfr[j], acc[i][j], 0, 0, 0);
        }
    }
#pragma unroll
    for (int i = 0; i < 4; i++)
#pragma unroll
        for (int j = 0; j < 4; j++)
#pragma unroll
            for (int r = 0; r < 4; r++) {
                int row = m0 + wr + i * 16 + lq * 4 + r;
                int col = n0 + wc + j * 16 + lr;
                if constexpr (sizeof(OUT_T) == 2)
                    C[(size_t)row * N + col] = f2bf(acc[i][j][r]);
                else
                    C[(size_t)row * N + col] = acc[i][j][r];
            }
}

// ==========================================================================
// RMS-norm + RoPE on Q/K inside QKV (row stride 4096), in place (bf16).
// One wave per 128-elem head row. Q also scaled by D^-0.5 * log2(e).
// ==========================================================================
__global__ __launch_bounds__(256) void norm_rope(u16* __restrict__ QKV,
                                                 const float* __restrict__ cosb,
                                                 const float* __restrict__ sinb,
                                                 const float* __restrict__ qw,
                                                 const float* __restrict__ kw) {
    const int tid = threadIdx.x;
    const int wave = tid >> 6, lane = tid & 63;
    const int t = blockIdx.x * 4 + wave;  // 0..98303
    u16* ptr;
    const float* w;
    float scale;
    int bs;
    if (t < 65536) {
        bs = t >> 4;
        ptr = QKV + (size_t)bs * 4096 + (t & 15) * 128;
        w = qw;
        scale = 0.08838834764831845f * 1.4426950408889634f;  // D^-0.5 * log2(e)
    } else {
        int t2 = t - 65536;
        bs = t2 >> 3;
        ptr = QKV + (size_t)bs * 4096 + 2048 + (t2 & 7) * 128;
        w = kw;
        scale = 1.0f;
    }
    const int d = lane * 2;
    u32 xv = *(const u32*)(ptr + d);
    float x0 = bf2f((u16)(xv & 0xffff)), x1 = bf2f((u16)(xv >> 16));
    float ss = x0 * x0 + x1 * x1;
#pragma unroll
    for (int off = 1; off < 64; off <<= 1) ss += __shfl_xor(ss, off);
    float rn = rsqrtf(ss * (1.0f / 128.0f) + 1e-6f);
    float2 wv = *(const float2*)(w + d);
    float y0 = x0 * rn * wv.x;
    float y1 = x1 * rn * wv.y;
    float p0 = __shfl_xor(y0, 32);
    float p1 = __shfl_xor(y1, 32);
    float sgn = (lane < 32) ? -1.0f : 1.0f;
    float2 cv = *(const float2*)(cosb + (size_t)bs * 128 + d);
    float2 sv = *(const float2*)(sinb + (size_t)bs * 128 + d);
    float o0 = (y0 * cv.x + sgn * p0 * sv.x) * scale;
    float o1 = (y1 * cv.y + sgn * p1 * sv.y) * scale;
    *(u32*)(ptr + d) = (u32)f2bf(o0) | ((u32)f2bf(o1) << 16);
}

// ==========================================================================
// Causal GQA flash attention, transposed-score formulation.
// Double-buffered async global_load_lds staging; XOR-swizzled LDS;
// P stays in registers (permuted-k PV MFMA). LDS = 64 KB -> 2 blocks/CU.
// Load balance: dispatch ids i and i+256 land on the same CU; qt is chosen
// complementary in b so each CU's resident pair sums to constant work
// (qt + (15-qt) = 17 key-tile-pairs) -> flat makespan.
// grid (S/128, NH, B), 512 thr = 8 waves x 16 q-rows; key tile 64.
// ==========================================================================
__global__ __launch_bounds__(512, 2) void attn_kernel(const u16* __restrict__ QKV,
                                                      const u16* __restrict__ Vt,
                                                      u16* __restrict__ O) {
    __shared__ __align__(16) u16 Ks[2][64 * 128];   // [key][d]   swizzled
    __shared__ __align__(16) u16 Vs[2][128 * 64];   // [d][key]   swizzled
    const int tid = threadIdx.x;
    const int wave = tid >> 6, lane = tid & 63;
    const int lr = lane & 15, lq = lane >> 4;
    const int h = blockIdx.y, b = blockIdx.z;
    // complementary pairing: same-CU pair (b=0,b=1) gets qt and 15-qt
    const int qt = (b == 0) ? (15 - blockIdx.x) : blockIdx.x;
    const int kv = h >> 1;
    const int q0 = qt * 128;
    const int wq = wave * 16;

    // async stage of one 64-key tile into buffer `buf` (4 instrs/wave)
    auto stage = [&](int buf, int k0s) {
#pragma unroll
        for (int j = 0; j < 2; j++) {   // Ks: 64 rows x 256 B
            int r = wave * 8 + j * 4 + (lane >> 4);
            int c = (lane & 15) ^ (r & 15);   // global chunk for this lane's slot
            __builtin_amdgcn_global_load_lds(
                (const AS1 void*)(QKV + (size_t)(b * 2048 + k0s + r) * 4096 + 2048 + kv * 128 + c * 8),
                (AS3 void*)(&Ks[buf][(wave * 8 + j * 4) * 128]), 16, 0, 0);
        }
#pragma unroll
        for (int j = 0; j < 2; j++) {   // Vs: 128 rows x 128 B
            int r = wave * 16 + j * 8 + (lane >> 3);
            int c = (lane & 7) ^ (r & 7);
            __builtin_amdgcn_global_load_lds(
                (const AS1 void*)(Vt + (size_t)((b * 8 + kv) * 128 + r) * 2048 + k0s + c * 8),
                (AS3 void*)(&Vs[buf][(wave * 16 + j * 8) * 64]), 16, 0, 0);
        }
    };

    // Q fragments in registers (B-operand: n=qrow on lr, k=d on lq*8+j)
    short8 qf[4];
#pragma unroll
    for (int t = 0; t < 4; t++)
        qf[t] = *(const short8*)(QKV + (size_t)(b * 2048 + q0 + wq + lr) * 4096 + h * 128 + t * 32 + lq * 8);

    floatx4 zf = {0.f, 0.f, 0.f, 0.f};
    floatx4 oacc[8];
#pragma unroll
    for (int jn = 0; jn < 8; jn++) oacc[jn] = zf;
    float mstate = -1e30f;
    float lstate = 0.f;

    const int nIter = (qt + 1) * 2;

    stage(0, 0);  // prologue: tile 0 -> buffer 0

    for (int kt = 0; kt < nIter; kt++) {
        const int k0 = kt * 64;
        const int cur = kt & 1;
        // (a) all waves done reading buf[cur^1]; (b) vmcnt drain -> tile kt
        // committed to buf[cur]. Loads for kt+1 (issued below) stay in
        // flight across the whole compute phase.
        __syncthreads();
        if (kt + 1 < nIter) stage(cur ^ 1, k0 + 64);

        // wave-level causal skip: this wave's 16 q-rows all < k0 -> zero tile
        if (k0 <= q0 + wq + 15) {
            const u16* KsC = &Ks[cur][0];
            const u16* VsC = &Vs[cur][0];
            // S^T = K @ Q^T : sacc[jm]; key = jm*16+lq*4+r, qrow = lr
            floatx4 sacc[4];
#pragma unroll
            for (int jm = 0; jm < 4; jm++) sacc[jm] = zf;
#pragma unroll
            for (int t = 0; t < 4; t++) {
                short8 a[4];
#pragma unroll
                for (int jm = 0; jm < 4; jm++)
                    a[jm] = *(const short8*)(KsC + (jm * 16 + lr) * 128 + (((t * 4 + lq) ^ lr) << 3));
#pragma unroll
                for (int jm = 0; jm < 4; jm++)
                    sacc[jm] = __builtin_amdgcn_mfma_f32_16x16x32_bf16(a[jm], qf[t], sacc[jm], 0, 0, 0);
            }

            // causal mask (wave-uniform branch)
            if (k0 + 63 > q0 + wq) {
#pragma unroll
                for (int jm = 0; jm < 4; jm++) {
                    int diff = (q0 + wq + lr) - (k0 + jm * 16 + lq * 4);
#pragma unroll
                    for (int r = 0; r < 4; r++)
                        if (r > diff) sacc[jm][r] = -1e30f;
                }
            }

            // online softmax per qrow (qrow on lane&15; reduce across quads)
            float mx = -1e30f;
#pragma unroll
            for (int jm = 0; jm < 4; jm++)
#pragma unroll
                for (int r = 0; r < 4; r++) mx = fmaxf(mx, sacc[jm][r]);
            mx = fmaxf(mx, __shfl_xor(mx, 16));
            mx = fmaxf(mx, __shfl_xor(mx, 32));
            float mnew = fmaxf(mstate, mx);
            float alpha = exp2f(mstate - mnew);
            mstate = mnew;
            float rs = 0.f;
#pragma unroll
            for (int jm = 0; jm < 4; jm++)
#pragma unroll
                for (int r = 0; r < 4; r++) {
                    float p = exp2f(sacc[jm][r] - mnew);
                    sacc[jm][r] = p;
                    rs += p;
                }
            rs += __shfl_xor(rs, 16);
            rs += __shfl_xor(rs, 32);
            lstate = lstate * alpha + rs;

            // pack P to bf16 in-register via v_cvt_pk_bf16_f32:
            // pb[jm] = keys jm*16+4lq+0..3, qrow=lr
            u64 pb[4];
#pragma unroll
            for (int jm = 0; jm < 4; jm++) {
                u32 lo = f2bf_pk(sacc[jm][0], sacc[jm][1]);
                u32 hi = f2bf_pk(sacc[jm][2], sacc[jm][3]);
                pb[jm] = (u64)lo | ((u64)hi << 32);
            }

            // rescale O: alpha at qrow=lr; oacc rows at qrow=lq*4+r
            float ao[4];
#pragma unroll
            for (int r = 0; r < 4; r++) ao[r] = __shfl(alpha, lq * 4 + r);
#pragma unroll
            for (int jn = 0; jn < 8; jn++)
#pragma unroll
                for (int r = 0; r < 4; r++) oacc[jn][r] *= ao[r];

            // O += P @ V, permuted k-order; A-frag straight from registers,
            // B-frag = V at the same permuted keys (two 8B LDS reads each).
#pragma unroll
            for (int t = 0; t < 2; t++) {
                union { short8 v; u64 q[2]; } pa;
                pa.q[0] = pb[2 * t];
                pa.q[1] = pb[2 * t + 1];
#pragma unroll
                for (int jn = 0; jn < 8; jn++) {
                    const u16* vrow = VsC + (jn * 16 + lr) * 64 + (lq & 1) * 4;
                    union { short8 v; u64 q[2]; } vb;
                    vb.q[0] = *(const u64*)(vrow + (((t * 4 + (lq >> 1)) ^ (lr & 7)) << 3));
                    vb.q[1] = *(const u64*)(vrow + (((t * 4 + 2 + (lq >> 1)) ^ (lr & 7)) << 3));
                    oacc[jn] = __builtin_amdgcn_mfma_f32_16x16x32_bf16(pa.v, vb.v, oacc[jn], 0, 0, 0);
                }
            }
        }
    }

    // epilogue: O / l   (l at qrow=lr -> transpose to qrow=lq*4+r)
    float lo[4];
#pragma unroll
    for (int r = 0; r < 4; r++) lo[r] = __shfl(lstate, lq * 4 + r);
#pragma unroll
    for (int jn = 0; jn < 8; jn++)
#pragma unroll
        for (int r = 0; r < 4; r++) {
            int row = q0 + wq + lq * 4 + r;
            O[(size_t)(b * 2048 + row) * 2048 + h * 128 + jn * 16 + lr] =
                f2bf(oacc[jn][r] / lo[r]);
        }
}

// ==========================================================================
extern "C" void kernel_launch(void* const* d_in, const int* in_sizes, int n_in,
                              void* d_out, int out_size, void* d_ws, size_t ws_size,
                              hipStream_t stream) {
    const float* X = (const float*)d_in[0];
    const float* cosb = (const float*)d_in[1];
    const float* sinb = (const float*)d_in[2];
    const float* Wq = (const float*)d_in[3];
    const float* Wk = (const float*)d_in[4];
    const float* Wv = (const float*)d_in[5];
    const float* Wo = (const float*)d_in[6];
    const float* qw = (const float*)d_in[7];
    const float* kw = (const float*)d_in[8];
    float* out = (float*)d_out;
    u16* ws = (u16*)d_ws;

    u16* WqkvT = ws;                    // 4096x2048 = 8388608
    u16* WoT = WqkvT + 8388608;         // 4194304
    u16* Xb = WoT + 4194304;            // 8388608 (dead after QKV GEMM)
    u16* QKVb = Xb + 8388608;           // 4096x4096 = 16777216
    u16* Vtb = QKVb + 16777216;         // 4194304
    u16* Ob = Xb;                       // alias
    // total 41,943,040 u16 = 83.9 MB

    dim3 tb(32, 32);
    transpose_wall<<<dim3(64, 64, 4), tb, 0, stream>>>(Wq, Wk, Wv, Wo, WqkvT, WoT);
    convert_x<<<8192, 256, 0, stream>>>(X, Xb);

    gemm_bt<u16><<<dim3(32, 32), 256, 0, stream>>>(Xb, WqkvT, QKVb, 4096, 4096, 2048);

    norm_rope<<<24576, 256, 0, stream>>>(QKVb, cosb, sinb, qw, kw);
    transpose_v<<<dim3(64, 4, 16), tb, 0, stream>>>(QKVb, Vtb);

    attn_kernel<<<dim3(16, 16, 2), 512, 0, stream>>>(QKVb, Vtb, Ob);

    gemm_bt<float><<<dim3(16, 32), 256, 0, stream>>>(Ob, WoT, out, 4096, 2048, 2048);
}